// Round 1
// baseline (380.397 us; speedup 1.0000x reference)
//
#include <hip/hip_runtime.h>
#include <hip/hip_bf16.h>

#define SEQ 2048
#define HD 64
#define NBH 32
#define SCALE 0.125f

typedef __attribute__((ext_vector_type(4))) float f32x4;
typedef __attribute__((ext_vector_type(8))) short bf16x8;

// float -> bf16 (round-to-nearest-even), bit-exact, no dependence on __hip_bfloat16 internals
__device__ inline short f2bf(float f) {
    unsigned u = __builtin_bit_cast(unsigned, f);
    unsigned r = u + 0x7FFFu + ((u >> 16) & 1u);
    return (short)(r >> 16);
}

// Detect mask element size (1-byte bool/int8 vs 4-byte int32/float32).
// Byte at offset S*S-1: under 1-byte storage it's mask[2047][2047] (diag, True -> nonzero);
// under 4-byte storage it's the high byte of element (row 511, col 2047) which is
// causally masked (col>row) -> 0.
__global__ void detect_mask_kernel(const unsigned char* __restrict__ m, int n, int* flag) {
    if (threadIdx.x == 0) *flag = (m[n - 1] != 0) ? 1 : 4;
}

__global__ __launch_bounds__(256)
void attn_kernel(const float* __restrict__ Q, const float* __restrict__ K,
                 const float* __restrict__ V, const unsigned char* __restrict__ mask,
                 const int* __restrict__ flag, float* __restrict__ Out) {
    __shared__ short plds[4][16][40];   // per-wave P transpose tile, stride 40 shorts (80B, 16B-aligned rows)

    const int esz  = *flag;
    const int bh   = blockIdx.y;
    const int wid  = threadIdx.x >> 6;
    const int lane = threadIdx.x & 63;
    const int l16  = lane & 15;
    const int hi   = lane >> 4;        // 0..3
    const int q0   = blockIdx.x * 64 + wid * 16;

    const size_t base = (size_t)bh * SEQ * HD;
    const float* Qb = Q + base;
    const float* Kb = K + base;
    const float* Vb = V + base;
    const unsigned int* mask32 = (const unsigned int*)mask;

    // ---- Q fragments (A layout: row=l16, k=hi*8+i (+32 per chunk)), fp32->bf16 ----
    bf16x8 qf[2];
    {
        const float* qp = Qb + (size_t)(q0 + l16) * HD + hi * 8;
        f32x4 a0 = *(const f32x4*)(qp);
        f32x4 a1 = *(const f32x4*)(qp + 4);
        f32x4 a2 = *(const f32x4*)(qp + 32);
        f32x4 a3 = *(const f32x4*)(qp + 36);
        #pragma unroll
        for (int i = 0; i < 4; ++i) {
            qf[0][i]     = f2bf(a0[i]);
            qf[0][4 + i] = f2bf(a1[i]);
            qf[1][i]     = f2bf(a2[i]);
            qf[1][4 + i] = f2bf(a3[i]);
        }
    }

    f32x4 acc_o[4] = {f32x4{0,0,0,0}, f32x4{0,0,0,0}, f32x4{0,0,0,0}, f32x4{0,0,0,0}};
    float m_run[4], l_run[4];
    #pragma unroll
    for (int j = 0; j < 4; ++j) { m_run[j] = -__builtin_inff(); l_run[j] = 0.f; }

    const int kv_end = q0 + 16;   // causal: keys beyond the q-tile are all-masked
    for (int kv = 0; kv < kv_end; kv += 32) {
        // ---- QK^T: S[16q][32k] in two 16x16 accumulators ----
        f32x4 acc_s[2] = {f32x4{0,0,0,0}, f32x4{0,0,0,0}};
        #pragma unroll
        for (int t = 0; t < 2; ++t) {
            const float* kp = Kb + (size_t)(kv + 16 * t + l16) * HD + hi * 8;
            f32x4 b0 = *(const f32x4*)(kp);
            f32x4 b1 = *(const f32x4*)(kp + 4);
            f32x4 b2 = *(const f32x4*)(kp + 32);
            f32x4 b3 = *(const f32x4*)(kp + 36);
            bf16x8 kf0, kf1;
            #pragma unroll
            for (int i = 0; i < 4; ++i) {
                kf0[i]     = f2bf(b0[i]);
                kf0[4 + i] = f2bf(b1[i]);
                kf1[i]     = f2bf(b2[i]);
                kf1[4 + i] = f2bf(b3[i]);
            }
            acc_s[t] = __builtin_amdgcn_mfma_f32_16x16x32_bf16(qf[0], kf0, acc_s[t], 0, 0, 0);
            acc_s[t] = __builtin_amdgcn_mfma_f32_16x16x32_bf16(qf[1], kf1, acc_s[t], 0, 0, 0);
        }

        // ---- mask + scale (C layout: lane holds rows q0+hi*4+j, col kv+16t+l16) ----
        float s[2][4];
        #pragma unroll
        for (int t = 0; t < 2; ++t) {
            const int k = kv + 16 * t + l16;
            #pragma unroll
            for (int j = 0; j < 4; ++j) {
                const int qrow = q0 + hi * 4 + j;
                const size_t midx = (size_t)qrow * SEQ + k;
                const bool mv = (esz == 1) ? (mask[midx] != 0) : (mask32[midx] != 0);
                s[t][j] = mv ? acc_s[t][j] * SCALE : -__builtin_inff();
            }
        }

        // ---- online softmax (row reductions across the 16 lanes of each group) ----
        float mnew[4], r[4];
        #pragma unroll
        for (int j = 0; j < 4; ++j) {
            float v = fmaxf(s[0][j], s[1][j]);
            #pragma unroll
            for (int off = 1; off < 16; off <<= 1)
                v = fmaxf(v, __shfl_xor(v, off));
            mnew[j] = fmaxf(m_run[j], v);
            r[j] = (m_run[j] > -__builtin_inff()) ? __expf(m_run[j] - mnew[j]) : 0.f;
        }
        float p[2][4];
        #pragma unroll
        for (int j = 0; j < 4; ++j) {
            float ps = 0.f;
            #pragma unroll
            for (int t = 0; t < 2; ++t) {
                p[t][j] = (s[t][j] > -__builtin_inff()) ? __expf(s[t][j] - mnew[j]) : 0.f;
                ps += p[t][j];
            }
            #pragma unroll
            for (int off = 1; off < 16; off <<= 1)
                ps += __shfl_xor(ps, off);
            l_run[j] = l_run[j] * r[j] + ps;
            m_run[j] = mnew[j];
            #pragma unroll
            for (int t2 = 0; t2 < 4; ++t2) acc_o[t2][j] *= r[j];
        }

        // ---- P: C layout -> A layout via wave-private LDS (no barrier: single-wave tile,
        //      waves have divergent trip counts so __syncthreads here would deadlock) ----
        #pragma unroll
        for (int t = 0; t < 2; ++t)
            #pragma unroll
            for (int j = 0; j < 4; ++j)
                plds[wid][hi * 4 + j][16 * t + l16] = f2bf(p[t][j]);
        bf16x8 pa = *(bf16x8*)&plds[wid][l16][hi * 8];

        // ---- PV: O[16q][64d] += P[16q][32k] * V[32k][64d], 4 d-tiles ----
        #pragma unroll
        for (int t2 = 0; t2 < 4; ++t2) {
            const float* vp = Vb + (size_t)(kv + hi * 8) * HD + 16 * t2 + l16;
            bf16x8 vf;
            #pragma unroll
            for (int i = 0; i < 8; ++i) vf[i] = f2bf(vp[(size_t)i * HD]);
            acc_o[t2] = __builtin_amdgcn_mfma_f32_16x16x32_bf16(pa, vf, acc_o[t2], 0, 0, 0);
        }
    }

    // ---- epilogue: divide by l, store fp32 ----
    #pragma unroll
    for (int j = 0; j < 4; ++j) {
        const float inv = 1.f / l_run[j];
        const int qrow = q0 + hi * 4 + j;
        float* op = Out + base + (size_t)qrow * HD + l16;
        #pragma unroll
        for (int t2 = 0; t2 < 4; ++t2)
            op[16 * t2] = acc_o[t2][j] * inv;
    }
}

extern "C" void kernel_launch(void* const* d_in, const int* in_sizes, int n_in,
                              void* d_out, int out_size, void* d_ws, size_t ws_size,
                              hipStream_t stream) {
    const float* Q = (const float*)d_in[0];
    const float* K = (const float*)d_in[1];
    const float* V = (const float*)d_in[2];
    const unsigned char* mask = (const unsigned char*)d_in[3];
    int* flag = (int*)d_ws;

    detect_mask_kernel<<<dim3(1), dim3(64), 0, stream>>>(mask, in_sizes[3], flag);

    dim3 grid(SEQ / 64, NBH);
    attn_kernel<<<grid, dim3(256), 0, stream>>>(Q, K, V, mask, flag, (float*)d_out);
}

// Round 2
// 257.718 us; speedup vs baseline: 1.4760x; 1.4760x over previous
//
#include <hip/hip_runtime.h>
#include <hip/hip_bf16.h>

#define SEQ 2048
#define HD 64
#define NBH 32
#define SCALE 0.125f

typedef __attribute__((ext_vector_type(4))) float f32x4;
typedef __attribute__((ext_vector_type(8))) short bf16x8;

__device__ inline short f2bf(float f) {
    unsigned u = __builtin_bit_cast(unsigned, f);
    unsigned r = u + 0x7FFFu + ((u >> 16) & 1u);
    return (short)(r >> 16);
}

// Detect mask element size (1-byte bool vs 4-byte). Byte at offset S*S-1:
// 1-byte storage -> diag element (2047,2047) = True -> nonzero; 4-byte storage ->
// high byte of causally-masked element (row 511, col 2047) -> 0.
__global__ void detect_mask_kernel(const unsigned char* __restrict__ m, int n, int* flag) {
    if (threadIdx.x == 0) *flag = (m[n - 1] != 0) ? 1 : 4;
}

// mask[2048][2048] -> bits[2048][64] dwords (bit b of word w = mask[row][w*32+b])
__global__ __launch_bounds__(256)
void bitpack_mask_kernel(const unsigned char* __restrict__ m, const int* __restrict__ flag,
                         unsigned* __restrict__ bits) {
    const int idx = blockIdx.x * 256 + threadIdx.x;   // 2048*64 words
    const int row = idx >> 6, w = idx & 63;
    const size_t base = (size_t)row * SEQ + w * 32;
    unsigned word = 0;
    if (*flag == 1) {
        #pragma unroll
        for (int b = 0; b < 32; ++b) word |= (unsigned)(m[base + b] != 0) << b;
    } else {
        const unsigned* m32 = (const unsigned*)m;
        #pragma unroll
        for (int b = 0; b < 32; ++b) word |= (unsigned)(m32[base + b] != 0) << b;
    }
    bits[idx] = word;
}

__global__ __launch_bounds__(256)
void convert_k_kernel(const float* __restrict__ K, short* __restrict__ Kb) {
    const size_t i = ((size_t)blockIdx.x * 256 + threadIdx.x) * 8;
    f32x4 a = *(const f32x4*)(K + i);
    f32x4 b = *(const f32x4*)(K + i + 4);
    bf16x8 o;
    #pragma unroll
    for (int j = 0; j < 4; ++j) { o[j] = f2bf(a[j]); o[4 + j] = f2bf(b[j]); }
    *(bf16x8*)(Kb + i) = o;
}

// V[bh][s][d] fp32 -> Vt[bh][d][s] bf16 via LDS tile transpose
__global__ __launch_bounds__(256)
void transpose_v_kernel(const float* __restrict__ V, short* __restrict__ Vt) {
    __shared__ short t[64][65];
    const int bh = blockIdx.y, s0 = blockIdx.x * 64, tid = threadIdx.x;
    const float* Vb = V + (size_t)bh * SEQ * HD;
    const int sr = tid >> 6, d = tid & 63;
    #pragma unroll
    for (int i = 0; i < 16; ++i) {
        const int s = i * 4 + sr;
        t[s][d] = f2bf(Vb[(size_t)(s0 + s) * HD + d]);
    }
    __syncthreads();
    short* o = Vt + (size_t)bh * HD * SEQ;
    const int dr = tid >> 6, sl = tid & 63;
    #pragma unroll
    for (int i = 0; i < 16; ++i) {
        const int dd = i * 4 + dr;
        o[(size_t)dd * SEQ + s0 + sl] = t[sl][dd];
    }
}

__global__ __launch_bounds__(256)
void attn_bf16_kernel(const float* __restrict__ Q, const short* __restrict__ Kb,
                      const short* __restrict__ Vt, const unsigned* __restrict__ bits,
                      float* __restrict__ Out) {
    __shared__ short plds[4][16][40];

    const int bh   = blockIdx.y;
    const int wid  = threadIdx.x >> 6;
    const int lane = threadIdx.x & 63;
    const int l16  = lane & 15;
    const int hi   = lane >> 4;
    const int qb   = gridDim.x - 1 - blockIdx.x;   // big causal blocks dispatched first
    const int q0   = qb * 64 + wid * 16;

    const size_t base = (size_t)bh * SEQ * HD;
    const short* Kbb = Kb + base;
    const short* Vtb = Vt + base;

    // Q fragment, SCALE folded into the bf16 conversion (0.125 is exact in bf16)
    bf16x8 qf[2];
    {
        const float* qp = Q + base + (size_t)(q0 + l16) * HD + hi * 8;
        f32x4 a0 = *(const f32x4*)(qp);
        f32x4 a1 = *(const f32x4*)(qp + 4);
        f32x4 a2 = *(const f32x4*)(qp + 32);
        f32x4 a3 = *(const f32x4*)(qp + 36);
        #pragma unroll
        for (int i = 0; i < 4; ++i) {
            qf[0][i]     = f2bf(a0[i] * SCALE);
            qf[0][4 + i] = f2bf(a1[i] * SCALE);
            qf[1][i]     = f2bf(a2[i] * SCALE);
            qf[1][4 + i] = f2bf(a3[i] * SCALE);
        }
    }

    f32x4 acc_o[4] = {f32x4{0,0,0,0}, f32x4{0,0,0,0}, f32x4{0,0,0,0}, f32x4{0,0,0,0}};
    float m_run[4], l_run[4];
    #pragma unroll
    for (int j = 0; j < 4; ++j) { m_run[j] = -__builtin_inff(); l_run[j] = 0.f; }

    const int kv_end = q0 + 16;
    #pragma unroll 2
    for (int kv = 0; kv < kv_end; kv += 32) {
        // ---- vector loads: K (4x16B), V^T (4x16B), mask words (4 dwords, L2-resident) ----
        bf16x8 kf00 = *(const bf16x8*)(Kbb + (size_t)(kv + l16) * HD + hi * 8);
        bf16x8 kf01 = *(const bf16x8*)(Kbb + (size_t)(kv + l16) * HD + 32 + hi * 8);
        bf16x8 kf10 = *(const bf16x8*)(Kbb + (size_t)(kv + 16 + l16) * HD + hi * 8);
        bf16x8 kf11 = *(const bf16x8*)(Kbb + (size_t)(kv + 16 + l16) * HD + 32 + hi * 8);
        bf16x8 vf[4];
        #pragma unroll
        for (int t2 = 0; t2 < 4; ++t2)
            vf[t2] = *(const bf16x8*)(Vtb + (size_t)(16 * t2 + l16) * SEQ + kv + hi * 8);
        unsigned mw[4];
        #pragma unroll
        for (int j = 0; j < 4; ++j)
            mw[j] = bits[(size_t)(q0 + hi * 4 + j) * (SEQ / 32) + (kv >> 5)];

        // ---- QK^T ----
        f32x4 acc_s[2] = {f32x4{0,0,0,0}, f32x4{0,0,0,0}};
        acc_s[0] = __builtin_amdgcn_mfma_f32_16x16x32_bf16(qf[0], kf00, acc_s[0], 0, 0, 0);
        acc_s[0] = __builtin_amdgcn_mfma_f32_16x16x32_bf16(qf[1], kf01, acc_s[0], 0, 0, 0);
        acc_s[1] = __builtin_amdgcn_mfma_f32_16x16x32_bf16(qf[0], kf10, acc_s[1], 0, 0, 0);
        acc_s[1] = __builtin_amdgcn_mfma_f32_16x16x32_bf16(qf[1], kf11, acc_s[1], 0, 0, 0);

        // ---- mask (bit t*16+l16 of row word) ----
        float s[2][4];
        #pragma unroll
        for (int t = 0; t < 2; ++t)
            #pragma unroll
            for (int j = 0; j < 4; ++j)
                s[t][j] = ((mw[j] >> (16 * t + l16)) & 1u) ? acc_s[t][j] : -__builtin_inff();

        // ---- online softmax ----
        float mnew[4], r[4];
        #pragma unroll
        for (int j = 0; j < 4; ++j) {
            float v = fmaxf(s[0][j], s[1][j]);
            #pragma unroll
            for (int off = 1; off < 16; off <<= 1)
                v = fmaxf(v, __shfl_xor(v, off));
            mnew[j] = fmaxf(m_run[j], v);
            r[j] = (m_run[j] > -__builtin_inff()) ? __expf(m_run[j] - mnew[j]) : 0.f;
        }
        float p[2][4];
        #pragma unroll
        for (int j = 0; j < 4; ++j) {
            float ps = 0.f;
            #pragma unroll
            for (int t = 0; t < 2; ++t) {
                p[t][j] = (s[t][j] > -__builtin_inff()) ? __expf(s[t][j] - mnew[j]) : 0.f;
                ps += p[t][j];
            }
            #pragma unroll
            for (int off = 1; off < 16; off <<= 1)
                ps += __shfl_xor(ps, off);
            l_run[j] = l_run[j] * r[j] + ps;
            m_run[j] = mnew[j];
            #pragma unroll
            for (int t2 = 0; t2 < 4; ++t2) acc_o[t2][j] *= r[j];
        }

        // ---- P: C->A layout via wave-private LDS (no barrier needed) ----
        #pragma unroll
        for (int t = 0; t < 2; ++t)
            #pragma unroll
            for (int j = 0; j < 4; ++j)
                plds[wid][hi * 4 + j][16 * t + l16] = f2bf(p[t][j]);
        bf16x8 pa = *(bf16x8*)&plds[wid][l16][hi * 8];

        // ---- PV ----
        #pragma unroll
        for (int t2 = 0; t2 < 4; ++t2)
            acc_o[t2] = __builtin_amdgcn_mfma_f32_16x16x32_bf16(pa, vf[t2], acc_o[t2], 0, 0, 0);
    }

    #pragma unroll
    for (int j = 0; j < 4; ++j) {
        const float inv = 1.f / l_run[j];
        const int qrow = q0 + hi * 4 + j;
        float* op = Out + base + (size_t)qrow * HD + l16;
        #pragma unroll
        for (int t2 = 0; t2 < 4; ++t2)
            op[16 * t2] = acc_o[t2][j] * inv;
    }
}

// ---------------- fallback (round-1 kernel) if ws too small ----------------
__global__ __launch_bounds__(256)
void attn_kernel(const float* __restrict__ Q, const float* __restrict__ K,
                 const float* __restrict__ V, const unsigned char* __restrict__ mask,
                 const int* __restrict__ flag, float* __restrict__ Out) {
    __shared__ short plds[4][16][40];
    const int esz  = *flag;
    const int bh   = blockIdx.y;
    const int wid  = threadIdx.x >> 6;
    const int lane = threadIdx.x & 63;
    const int l16  = lane & 15;
    const int hi   = lane >> 4;
    const int q0   = blockIdx.x * 64 + wid * 16;
    const size_t base = (size_t)bh * SEQ * HD;
    const float* Qb = Q + base;
    const float* Kb = K + base;
    const float* Vb = V + base;
    const unsigned int* mask32 = (const unsigned int*)mask;
    bf16x8 qf[2];
    {
        const float* qp = Qb + (size_t)(q0 + l16) * HD + hi * 8;
        f32x4 a0 = *(const f32x4*)(qp);
        f32x4 a1 = *(const f32x4*)(qp + 4);
        f32x4 a2 = *(const f32x4*)(qp + 32);
        f32x4 a3 = *(const f32x4*)(qp + 36);
        #pragma unroll
        for (int i = 0; i < 4; ++i) {
            qf[0][i] = f2bf(a0[i]); qf[0][4 + i] = f2bf(a1[i]);
            qf[1][i] = f2bf(a2[i]); qf[1][4 + i] = f2bf(a3[i]);
        }
    }
    f32x4 acc_o[4] = {f32x4{0,0,0,0}, f32x4{0,0,0,0}, f32x4{0,0,0,0}, f32x4{0,0,0,0}};
    float m_run[4], l_run[4];
    #pragma unroll
    for (int j = 0; j < 4; ++j) { m_run[j] = -__builtin_inff(); l_run[j] = 0.f; }
    const int kv_end = q0 + 16;
    for (int kv = 0; kv < kv_end; kv += 32) {
        f32x4 acc_s[2] = {f32x4{0,0,0,0}, f32x4{0,0,0,0}};
        #pragma unroll
        for (int t = 0; t < 2; ++t) {
            const float* kp = Kb + (size_t)(kv + 16 * t + l16) * HD + hi * 8;
            f32x4 b0 = *(const f32x4*)(kp);
            f32x4 b1 = *(const f32x4*)(kp + 4);
            f32x4 b2 = *(const f32x4*)(kp + 32);
            f32x4 b3 = *(const f32x4*)(kp + 36);
            bf16x8 kf0, kf1;
            #pragma unroll
            for (int i = 0; i < 4; ++i) {
                kf0[i] = f2bf(b0[i]); kf0[4 + i] = f2bf(b1[i]);
                kf1[i] = f2bf(b2[i]); kf1[4 + i] = f2bf(b3[i]);
            }
            acc_s[t] = __builtin_amdgcn_mfma_f32_16x16x32_bf16(qf[0], kf0, acc_s[t], 0, 0, 0);
            acc_s[t] = __builtin_amdgcn_mfma_f32_16x16x32_bf16(qf[1], kf1, acc_s[t], 0, 0, 0);
        }
        float s[2][4];
        #pragma unroll
        for (int t = 0; t < 2; ++t) {
            const int k = kv + 16 * t + l16;
            #pragma unroll
            for (int j = 0; j < 4; ++j) {
                const int qrow = q0 + hi * 4 + j;
                const size_t midx = (size_t)qrow * SEQ + k;
                const bool mv = (esz == 1) ? (mask[midx] != 0) : (mask32[midx] != 0);
                s[t][j] = mv ? acc_s[t][j] * SCALE : -__builtin_inff();
            }
        }
        float mnew[4], r[4];
        #pragma unroll
        for (int j = 0; j < 4; ++j) {
            float v = fmaxf(s[0][j], s[1][j]);
            #pragma unroll
            for (int off = 1; off < 16; off <<= 1) v = fmaxf(v, __shfl_xor(v, off));
            mnew[j] = fmaxf(m_run[j], v);
            r[j] = (m_run[j] > -__builtin_inff()) ? __expf(m_run[j] - mnew[j]) : 0.f;
        }
        float p[2][4];
        #pragma unroll
        for (int j = 0; j < 4; ++j) {
            float ps = 0.f;
            #pragma unroll
            for (int t = 0; t < 2; ++t) {
                p[t][j] = (s[t][j] > -__builtin_inff()) ? __expf(s[t][j] - mnew[j]) : 0.f;
                ps += p[t][j];
            }
            #pragma unroll
            for (int off = 1; off < 16; off <<= 1) ps += __shfl_xor(ps, off);
            l_run[j] = l_run[j] * r[j] + ps;
            m_run[j] = mnew[j];
            #pragma unroll
            for (int t2 = 0; t2 < 4; ++t2) acc_o[t2][j] *= r[j];
        }
        #pragma unroll
        for (int t = 0; t < 2; ++t)
            #pragma unroll
            for (int j = 0; j < 4; ++j)
                plds[wid][hi * 4 + j][16 * t + l16] = f2bf(p[t][j]);
        bf16x8 pa = *(bf16x8*)&plds[wid][l16][hi * 8];
        #pragma unroll
        for (int t2 = 0; t2 < 4; ++t2) {
            const float* vp = Vb + (size_t)(kv + hi * 8) * HD + 16 * t2 + l16;
            bf16x8 vf;
            #pragma unroll
            for (int i = 0; i < 8; ++i) vf[i] = f2bf(vp[(size_t)i * HD]);
            acc_o[t2] = __builtin_amdgcn_mfma_f32_16x16x32_bf16(pa, vf, acc_o[t2], 0, 0, 0);
        }
    }
    #pragma unroll
    for (int j = 0; j < 4; ++j) {
        const float inv = 1.f / l_run[j];
        const int qrow = q0 + hi * 4 + j;
        float* op = Out + base + (size_t)qrow * HD + l16;
        #pragma unroll
        for (int t2 = 0; t2 < 4; ++t2) op[16 * t2] = acc_o[t2][j] * inv;
    }
}

extern "C" void kernel_launch(void* const* d_in, const int* in_sizes, int n_in,
                              void* d_out, int out_size, void* d_ws, size_t ws_size,
                              hipStream_t stream) {
    const float* Q = (const float*)d_in[0];
    const float* K = (const float*)d_in[1];
    const float* V = (const float*)d_in[2];
    const unsigned char* mask = (const unsigned char*)d_in[3];

    const size_t bitsB = (size_t)SEQ * (SEQ / 32) * 4;          // 512 KB
    const size_t kvB   = (size_t)NBH * SEQ * HD * 2;            // 8 MB
    const size_t need  = bitsB + 2 * kvB + 256;

    if (ws_size >= need) {
        unsigned* bits = (unsigned*)d_ws;
        short* Kb = (short*)((char*)d_ws + bitsB);
        short* Vt = (short*)((char*)d_ws + bitsB + kvB);
        int* flag = (int*)((char*)d_ws + bitsB + 2 * kvB);

        detect_mask_kernel<<<dim3(1), dim3(64), 0, stream>>>(mask, in_sizes[3], flag);
        bitpack_mask_kernel<<<dim3(SEQ * (SEQ / 32) / 256), dim3(256), 0, stream>>>(mask, flag, bits);
        convert_k_kernel<<<dim3((NBH * SEQ * HD / 8) / 256), dim3(256), 0, stream>>>(K, (short*)Kb);
        transpose_v_kernel<<<dim3(SEQ / 64, NBH), dim3(256), 0, stream>>>(V, (short*)Vt);
        attn_bf16_kernel<<<dim3(SEQ / 64, NBH), dim3(256), 0, stream>>>(Q, Kb, Vt, bits, (float*)d_out);
    } else {
        int* flag = (int*)d_ws;
        detect_mask_kernel<<<dim3(1), dim3(64), 0, stream>>>(mask, in_sizes[3], flag);
        attn_kernel<<<dim3(SEQ / 64, NBH), dim3(256), 0, stream>>>(Q, K, V, mask, flag, (float*)d_out);
    }
}

// Round 4
// 144.636 us; speedup vs baseline: 2.6300x; 1.7818x over previous
//
#include <hip/hip_runtime.h>
#include <hip/hip_bf16.h>

#define SEQ 2048
#define HD 64
#define NBH 32
#define SCALE 0.125f
#define QSC 0.18033688011112042f   // 0.125 * log2(e)  -> softmax in exp2 domain

typedef __attribute__((ext_vector_type(4)))  float    f32x4;
typedef __attribute__((ext_vector_type(16))) float    f32x16;
typedef __attribute__((ext_vector_type(8)))  short    bf16x8;
typedef __attribute__((ext_vector_type(4)))  unsigned u32x4;

__device__ inline short f2bf(float f) {
    unsigned u = __builtin_bit_cast(unsigned, f);
    unsigned r = u + 0x7FFFu + ((u >> 16) & 1u);
    return (short)(r >> 16);
}

// packed f32 pair -> bf16 pair (RNE), single VOP3, per-lane (no cross-lane hazard)
__device__ inline unsigned cvt2(float lo, float hi) {
    unsigned d;
    asm("v_cvt_pk_bf16_f32 %0, %1, %2" : "=v"(d) : "v"(lo), "v"(hi));
    return d;
}

// Detect mask element size (1-byte bool vs 4-byte). Byte at offset S*S-1:
// 1-byte -> diag (2047,2047)=True -> nonzero; 4-byte -> high byte of causally
// masked element (row 511, col 2047) -> 0.
__global__ void detect_mask_kernel(const unsigned char* __restrict__ m, int n, int* flag) {
    if (threadIdx.x == 0) *flag = (m[n - 1] != 0) ? 1 : 4;
}

// mask[2048][2048] -> bitsT[64][2048]: bitsT[w][row] bit b = mask[row][w*32+b]
__global__ __launch_bounds__(256)
void bitpack_mask_kernel(const unsigned char* __restrict__ m, const int* __restrict__ flag,
                         unsigned* __restrict__ bits) {
    const int idx = blockIdx.x * 256 + threadIdx.x;   // 2048*64 words
    const int row = idx >> 6, w = idx & 63;
    const size_t base = (size_t)row * SEQ + w * 32;
    unsigned word = 0;
    if (*flag == 1) {
        #pragma unroll
        for (int b = 0; b < 32; ++b) word |= (unsigned)(m[base + b] != 0) << b;
    } else {
        const unsigned* m32 = (const unsigned*)m;
        #pragma unroll
        for (int b = 0; b < 32; ++b) word |= (unsigned)(m32[base + b] != 0) << b;
    }
    bits[(size_t)w * SEQ + row] = word;
}

__global__ __launch_bounds__(256)
void convert_k_kernel(const float* __restrict__ K, short* __restrict__ Kb) {
    const size_t i = ((size_t)blockIdx.x * 256 + threadIdx.x) * 8;
    f32x4 a = *(const f32x4*)(K + i);
    f32x4 b = *(const f32x4*)(K + i + 4);
    bf16x8 o;
    #pragma unroll
    for (int j = 0; j < 4; ++j) { o[j] = f2bf(a[j]); o[4 + j] = f2bf(b[j]); }
    *(bf16x8*)(Kb + i) = o;
}

// V[bh][s][d] fp32 -> Vt[bh][s/32][d][s&31] bf16 (tiled so PV A-frag loads coalesce)
__global__ __launch_bounds__(256)
void transpose_v_kernel(const float* __restrict__ V, short* __restrict__ Vt) {
    __shared__ short t[64][65];
    const int bh = blockIdx.y, s0 = blockIdx.x * 64, tid = threadIdx.x;
    const float* Vb = V + (size_t)bh * SEQ * HD;
    const int sr = tid >> 6, d = tid & 63;
    #pragma unroll
    for (int i = 0; i < 16; ++i) {
        const int s = i * 4 + sr;
        t[s][d] = f2bf(Vb[(size_t)(s0 + s) * HD + d]);
    }
    __syncthreads();
    short* o = Vt + (size_t)bh * HD * SEQ;
    const int dr = tid >> 6, sl = tid & 63;
    #pragma unroll
    for (int i = 0; i < 16; ++i) {
        const int dd = i * 4 + dr;
        const int s = s0 + sl;
        o[(size_t)(s >> 5) * (HD * 32) + dd * 32 + (s & 31)] = t[sl][dd];
    }
}

// One wave = 32 q-rows. Swapped QK^T (mfma(K,Q)) -> lane owns q-row = lane&31;
// softmax fully in-register; cross-half traffic via __shfl_xor(.,32) only.
__global__ __launch_bounds__(64, 2)
void attn32_kernel(const float* __restrict__ Q, const short* __restrict__ Kb,
                   const short* __restrict__ Vt, const unsigned* __restrict__ bitsT,
                   float* __restrict__ Out) {
    const int bh = blockIdx.y;
    const int la = threadIdx.x & 31;   // q-row within tile / k,d row for A-frags
    const int h  = threadIdx.x >> 5;   // wave half
    const int qt = gridDim.x - 1 - blockIdx.x;   // longest blocks first
    const int q0 = qt * 32;
    const size_t base = (size_t)bh * SEQ * HD;

    // Q as MFMA B-operand: col=q=la, k-elem i of chunk j -> d = j*16 + h*8 + i
    bf16x8 qf[4];
    {
        const float* qp = Q + base + (size_t)(q0 + la) * HD + h * 8;
        #pragma unroll
        for (int j = 0; j < 4; ++j) {
            f32x4 a0 = *(const f32x4*)(qp + j * 16);
            f32x4 a1 = *(const f32x4*)(qp + j * 16 + 4);
            #pragma unroll
            for (int i = 0; i < 4; ++i) {
                qf[j][i]     = f2bf(a0[i] * QSC);
                qf[j][4 + i] = f2bf(a1[i] * QSC);
            }
        }
    }

    f32x16 acc_o0 = {0,0,0,0,0,0,0,0,0,0,0,0,0,0,0,0};
    f32x16 acc_o1 = {0,0,0,0,0,0,0,0,0,0,0,0,0,0,0,0};
    float m_run = -3e38f, l_run = 0.f;

    const short* Kbb = Kb + base;
    const short* Vtb = Vt + base;
    const unsigned* bq = bitsT + q0 + la;

    for (int kv = 0; kv < q0 + 32; kv += 32) {
        // ---- QK^T swapped: C[row = k-in-tile][col = q = la] ----
        const short* kp = Kbb + (size_t)(kv + la) * HD + h * 8;
        f32x16 s = {0,0,0,0,0,0,0,0,0,0,0,0,0,0,0,0};
        #pragma unroll
        for (int j = 0; j < 4; ++j) {
            bf16x8 kf = *(const bf16x8*)(kp + j * 16);
            s = __builtin_amdgcn_mfma_f32_32x32x16_bf16(kf, qf[j], s, 0, 0, 0);
        }

        // V^T A-frags (coalesced from tiled layout), issued early
        const short* vt = Vtb + (size_t)(kv >> 5) * (HD * 32) + la * 32 + h * 8;
        bf16x8 vf00 = *(const bf16x8*)(vt);
        bf16x8 vf01 = *(const bf16x8*)(vt + 16);
        bf16x8 vf10 = *(const bf16x8*)(vt + 32 * 32);
        bf16x8 vf11 = *(const bf16x8*)(vt + 32 * 32 + 16);

        const unsigned mw = bq[(size_t)(kv >> 5) * SEQ];

        // ---- row max over this lane's 16 regs (unmasked max is valid) + cross-half
        float mx = fmaxf(fmaxf(fmaxf(s[0], s[1]), fmaxf(s[2], s[3])),
                         fmaxf(fmaxf(s[4], s[5]), fmaxf(s[6], s[7])));
        mx = fmaxf(mx, fmaxf(fmaxf(fmaxf(s[8], s[9]), fmaxf(s[10], s[11])),
                             fmaxf(fmaxf(s[12], s[13]), fmaxf(s[14], s[15]))));
        mx = fmaxf(mx, __shfl_xor(mx, 32));
        const float mnew = fmaxf(m_run, mx);
        const float rsc = __builtin_amdgcn_exp2f(m_run - mnew);
        m_run = mnew;

        // ---- P = mask ? exp2(s - m) : 0   (k-row = (r&3) + 8*(r>>2) + 4h) ----
        const int bp = 4 * h;
        #pragma unroll
        for (int r = 0; r < 16; ++r) {
            float e = __builtin_amdgcn_exp2f(s[r] - mnew);
            s[r] = ((mw >> (bp + (r & 3) + 8 * (r >> 2))) & 1u) ? e : 0.f;
        }
        float ps = ((s[0] + s[1]) + (s[2] + s[3])) + ((s[4] + s[5]) + (s[6] + s[7]));
        ps += ((s[8] + s[9]) + (s[10] + s[11])) + ((s[12] + s[13]) + (s[14] + s[15]));
        ps += __shfl_xor(ps, 32);
        l_run = l_run * rsc + ps;
        #pragma unroll
        for (int r = 0; r < 16; ++r) { acc_o0[r] *= rsc; acc_o1[r] *= rsc; }

        // ---- pack P^T into B-frags (target: elem i of half h <-> k = 8h+i) ----
        // lane h=0 holds k {0..3}=s0..3, {8..11}=s4..7, {16..19}=s8..11, {24..27}=s12..15
        // lane h=1 holds the same +4. Cross-half exchange via shfl_xor(32).
        {
            unsigned a0 = cvt2(s[0], s[1]),  a1 = cvt2(s[2], s[3]);    // h=0: k0-3 | h=1: k4-7
            unsigned b0 = cvt2(s[4], s[5]),  b1 = cvt2(s[6], s[7]);    // h=0: k8-11| h=1: k12-15
            unsigned d0 = h ? a0 : b0;           // word my partner needs
            unsigned d1 = h ? a1 : b1;
            unsigned e0 = __shfl_xor(d0, 32);    // word I need from partner
            unsigned e1 = __shfl_xor(d1, 32);
            u32x4 t1 = h ? u32x4{e0, e1, b0, b1}    // h=1: [k8..11 , k12..15]
                         : u32x4{a0, a1, e0, e1};   // h=0: [k0..3  , k4..7  ]
            bf16x8 pb1 = __builtin_bit_cast(bf16x8, t1);

            unsigned a2 = cvt2(s[8], s[9]),   a3 = cvt2(s[10], s[11]); // k16-19 | k20-23
            unsigned b2 = cvt2(s[12], s[13]), b3 = cvt2(s[14], s[15]); // k24-27 | k28-31
            unsigned d2 = h ? a2 : b2;
            unsigned d3 = h ? a3 : b3;
            unsigned e2 = __shfl_xor(d2, 32);
            unsigned e3 = __shfl_xor(d3, 32);
            u32x4 t2 = h ? u32x4{e2, e3, b2, b3}
                         : u32x4{a2, a3, e2, e3};
            bf16x8 pb2 = __builtin_bit_cast(bf16x8, t2);

            // ---- PV: O^T[d][q] += V^T[d][k] * P^T[k][q] ----
            acc_o0 = __builtin_amdgcn_mfma_f32_32x32x16_bf16(vf00, pb1, acc_o0, 0, 0, 0);
            acc_o0 = __builtin_amdgcn_mfma_f32_32x32x16_bf16(vf01, pb2, acc_o0, 0, 0, 0);
            acc_o1 = __builtin_amdgcn_mfma_f32_32x32x16_bf16(vf10, pb1, acc_o1, 0, 0, 0);
            acc_o1 = __builtin_amdgcn_mfma_f32_32x32x16_bf16(vf11, pb2, acc_o1, 0, 0, 0);
        }
    }

    // ---- epilogue: O[q][d] = O^T[d][q] / l ----
    const float inv = 1.f / l_run;
    float* op = Out + base + (size_t)(q0 + la) * HD;
    #pragma unroll
    for (int r = 0; r < 16; ++r) {
        const int d0 = (r & 3) + 8 * (r >> 2) + 4 * h;
        op[d0]      = acc_o0[r] * inv;
        op[32 + d0] = acc_o1[r] * inv;
    }
}

// ---------------- fallback (round-1 kernel) if ws too small ----------------
__global__ __launch_bounds__(256)
void attn_kernel(const float* __restrict__ Q, const float* __restrict__ K,
                 const float* __restrict__ V, const unsigned char* __restrict__ mask,
                 const int* __restrict__ flag, float* __restrict__ Out) {
    __shared__ short plds[4][16][40];
    const int esz  = *flag;
    const int bh   = blockIdx.y;
    const int wid  = threadIdx.x >> 6;
    const int lane = threadIdx.x & 63;
    const int l16  = lane & 15;
    const int hi   = lane >> 4;
    const int q0   = blockIdx.x * 64 + wid * 16;
    const size_t base = (size_t)bh * SEQ * HD;
    const float* Qb = Q + base;
    const float* Kb = K + base;
    const float* Vb = V + base;
    const unsigned int* mask32 = (const unsigned int*)mask;
    bf16x8 qf[2];
    {
        const float* qp = Qb + (size_t)(q0 + l16) * HD + hi * 8;
        f32x4 a0 = *(const f32x4*)(qp);
        f32x4 a1 = *(const f32x4*)(qp + 4);
        f32x4 a2 = *(const f32x4*)(qp + 32);
        f32x4 a3 = *(const f32x4*)(qp + 36);
        #pragma unroll
        for (int i = 0; i < 4; ++i) {
            qf[0][i] = f2bf(a0[i]); qf[0][4 + i] = f2bf(a1[i]);
            qf[1][i] = f2bf(a2[i]); qf[1][4 + i] = f2bf(a3[i]);
        }
    }
    f32x4 acc_o[4] = {f32x4{0,0,0,0}, f32x4{0,0,0,0}, f32x4{0,0,0,0}, f32x4{0,0,0,0}};
    float m_run[4], l_run[4];
    #pragma unroll
    for (int j = 0; j < 4; ++j) { m_run[j] = -__builtin_inff(); l_run[j] = 0.f; }
    const int kv_end = q0 + 16;
    for (int kv = 0; kv < kv_end; kv += 32) {
        f32x4 acc_s[2] = {f32x4{0,0,0,0}, f32x4{0,0,0,0}};
        #pragma unroll
        for (int t = 0; t < 2; ++t) {
            const float* kp = Kb + (size_t)(kv + 16 * t + l16) * HD + hi * 8;
            f32x4 b0 = *(const f32x4*)(kp);
            f32x4 b1 = *(const f32x4*)(kp + 4);
            f32x4 b2 = *(const f32x4*)(kp + 32);
            f32x4 b3 = *(const f32x4*)(kp + 36);
            bf16x8 kf0, kf1;
            #pragma unroll
            for (int i = 0; i < 4; ++i) {
                kf0[i] = f2bf(b0[i]); kf0[4 + i] = f2bf(b1[i]);
                kf1[i] = f2bf(b2[i]); kf1[4 + i] = f2bf(b3[i]);
            }
            acc_s[t] = __builtin_amdgcn_mfma_f32_16x16x32_bf16(qf[0], kf0, acc_s[t], 0, 0, 0);
            acc_s[t] = __builtin_amdgcn_mfma_f32_16x16x32_bf16(qf[1], kf1, acc_s[t], 0, 0, 0);
        }
        float s[2][4];
        #pragma unroll
        for (int t = 0; t < 2; ++t) {
            const int k = kv + 16 * t + l16;
            #pragma unroll
            for (int j = 0; j < 4; ++j) {
                const int qrow = q0 + hi * 4 + j;
                const size_t midx = (size_t)qrow * SEQ + k;
                const bool mv = (esz == 1) ? (mask[midx] != 0) : (mask32[midx] != 0);
                s[t][j] = mv ? acc_s[t][j] * SCALE : -__builtin_inff();
            }
        }
        float mnew[4], r[4];
        #pragma unroll
        for (int j = 0; j < 4; ++j) {
            float v = fmaxf(s[0][j], s[1][j]);
            #pragma unroll
            for (int off = 1; off < 16; off <<= 1) v = fmaxf(v, __shfl_xor(v, off));
            mnew[j] = fmaxf(m_run[j], v);
            r[j] = (m_run[j] > -__builtin_inff()) ? __expf(m_run[j] - mnew[j]) : 0.f;
        }
        float p[2][4];
        #pragma unroll
        for (int j = 0; j < 4; ++j) {
            float ps = 0.f;
            #pragma unroll
            for (int t = 0; t < 2; ++t) {
                p[t][j] = (s[t][j] > -__builtin_inff()) ? __expf(s[t][j] - mnew[j]) : 0.f;
                ps += p[t][j];
            }
            #pragma unroll
            for (int off = 1; off < 16; off <<= 1) ps += __shfl_xor(ps, off);
            l_run[j] = l_run[j] * r[j] + ps;
            m_run[j] = mnew[j];
            #pragma unroll
            for (int t2 = 0; t2 < 4; ++t2) acc_o[t2][j] *= r[j];
        }
        #pragma unroll
        for (int t = 0; t < 2; ++t)
            #pragma unroll
            for (int j = 0; j < 4; ++j)
                plds[wid][hi * 4 + j][16 * t + l16] = f2bf(p[t][j]);
        bf16x8 pa = *(bf16x8*)&plds[wid][l16][hi * 8];
        #pragma unroll
        for (int t2 = 0; t2 < 4; ++t2) {
            const float* vp = Vb + (size_t)(kv + hi * 8) * HD + 16 * t2 + l16;
            bf16x8 vf;
            #pragma unroll
            for (int i = 0; i < 8; ++i) vf[i] = f2bf(vp[(size_t)i * HD]);
            acc_o[t2] = __builtin_amdgcn_mfma_f32_16x16x32_bf16(pa, vf, acc_o[t2], 0, 0, 0);
        }
    }
    #pragma unroll
    for (int j = 0; j < 4; ++j) {
        const float inv = 1.f / l_run[j];
        const int qrow = q0 + hi * 4 + j;
        float* op = Out + base + (size_t)qrow * HD + l16;
        #pragma unroll
        for (int t2 = 0; t2 < 4; ++t2) op[16 * t2] = acc_o[t2][j] * inv;
    }
}

extern "C" void kernel_launch(void* const* d_in, const int* in_sizes, int n_in,
                              void* d_out, int out_size, void* d_ws, size_t ws_size,
                              hipStream_t stream) {
    const float* Q = (const float*)d_in[0];
    const float* K = (const float*)d_in[1];
    const float* V = (const float*)d_in[2];
    const unsigned char* mask = (const unsigned char*)d_in[3];

    const size_t bitsB = (size_t)SEQ * (SEQ / 32) * 4;          // 512 KB
    const size_t kvB   = (size_t)NBH * SEQ * HD * 2;            // 8 MB
    const size_t need  = bitsB + 2 * kvB + 256;

    if (ws_size >= need) {
        unsigned* bits = (unsigned*)d_ws;
        short* Kb = (short*)((char*)d_ws + bitsB);
        short* Vt = (short*)((char*)d_ws + bitsB + kvB);
        int* flag = (int*)((char*)d_ws + bitsB + 2 * kvB);

        detect_mask_kernel<<<dim3(1), dim3(64), 0, stream>>>(mask, in_sizes[3], flag);
        bitpack_mask_kernel<<<dim3(SEQ * (SEQ / 32) / 256), dim3(256), 0, stream>>>(mask, flag, bits);
        convert_k_kernel<<<dim3((NBH * SEQ * HD / 8) / 256), dim3(256), 0, stream>>>(K, Kb);
        transpose_v_kernel<<<dim3(SEQ / 64, NBH), dim3(256), 0, stream>>>(V, Vt);
        attn32_kernel<<<dim3(SEQ / 32, NBH), dim3(64), 0, stream>>>(Q, Kb, Vt, bits, (float*)d_out);
    } else {
        int* flag = (int*)d_ws;
        detect_mask_kernel<<<dim3(1), dim3(64), 0, stream>>>(mask, in_sizes[3], flag);
        attn_kernel<<<dim3(SEQ / 64, NBH), dim3(256), 0, stream>>>(Q, K, V, mask, flag, (float*)d_out);
    }
}

// Round 5
// 111.397 us; speedup vs baseline: 3.4148x; 1.2984x over previous
//
#include <hip/hip_runtime.h>
#include <hip/hip_bf16.h>

#define SEQ 2048
#define HD 64
#define NBH 32
#define SCALE 0.125f
#define QSC 0.18033688011112042f   // 0.125 * log2(e)  -> softmax in exp2 domain

typedef __attribute__((ext_vector_type(4)))  float    f32x4;
typedef __attribute__((ext_vector_type(16))) float    f32x16;
typedef __attribute__((ext_vector_type(8)))  short    bf16x8;
typedef __attribute__((ext_vector_type(4)))  unsigned u32x4;

__device__ inline short f2bf(float f) {
    unsigned u = __builtin_bit_cast(unsigned, f);
    unsigned r = u + 0x7FFFu + ((u >> 16) & 1u);
    return (short)(r >> 16);
}

// packed f32 pair -> bf16 pair (RNE), single VOP3, per-lane
__device__ inline unsigned cvt2(float lo, float hi) {
    unsigned d;
    asm("v_cvt_pk_bf16_f32 %0, %1, %2" : "=v"(d) : "v"(lo), "v"(hi));
    return d;
}

// Detect mask element size (1-byte bool vs 4-byte). Byte at offset S*S-1:
// 1-byte -> diag (2047,2047)=True -> nonzero; 4-byte -> high byte of causally
// masked element (row 511, col 2047) -> 0.
__global__ void detect_mask_kernel(const unsigned char* __restrict__ m, int n, int* flag) {
    if (threadIdx.x == 0) *flag = (m[n - 1] != 0) ? 1 : 4;
}

// mask[2048][2048] -> bitsT[64][2048]: bitsT[w][row] bit b = mask[row][w*32+b]
__global__ __launch_bounds__(256)
void bitpack_mask_kernel(const unsigned char* __restrict__ m, const int* __restrict__ flag,
                         unsigned* __restrict__ bits) {
    const int idx = blockIdx.x * 256 + threadIdx.x;   // 2048*64 words
    const int row = idx >> 6, w = idx & 63;
    const size_t base = (size_t)row * SEQ + w * 32;
    unsigned word = 0;
    if (*flag == 1) {
        #pragma unroll
        for (int b = 0; b < 32; ++b) word |= (unsigned)(m[base + b] != 0) << b;
    } else {
        const unsigned* m32 = (const unsigned*)m;
        #pragma unroll
        for (int b = 0; b < 32; ++b) word |= (unsigned)(m32[base + b] != 0) << b;
    }
    bits[(size_t)w * SEQ + row] = word;
}

__global__ __launch_bounds__(256)
void convert_k_kernel(const float* __restrict__ K, short* __restrict__ Kb) {
    const size_t i = ((size_t)blockIdx.x * 256 + threadIdx.x) * 8;
    f32x4 a = *(const f32x4*)(K + i);
    f32x4 b = *(const f32x4*)(K + i + 4);
    bf16x8 o;
    #pragma unroll
    for (int j = 0; j < 4; ++j) { o[j] = f2bf(a[j]); o[4 + j] = f2bf(b[j]); }
    *(bf16x8*)(Kb + i) = o;
}

// V[bh][s][d] fp32 -> Vt[bh][s/32][d][s&31] bf16 (tiled so PV A-frag loads coalesce)
__global__ __launch_bounds__(256)
void transpose_v_kernel(const float* __restrict__ V, short* __restrict__ Vt) {
    __shared__ short t[64][65];
    const int bh = blockIdx.y, s0 = blockIdx.x * 64, tid = threadIdx.x;
    const float* Vb = V + (size_t)bh * SEQ * HD;
    const int sr = tid >> 6, d = tid & 63;
    #pragma unroll
    for (int i = 0; i < 16; ++i) {
        const int s = i * 4 + sr;
        t[s][d] = f2bf(Vb[(size_t)(s0 + s) * HD + d]);
    }
    __syncthreads();
    short* o = Vt + (size_t)bh * HD * SEQ;
    const int dr = tid >> 6, sl = tid & 63;
    #pragma unroll
    for (int i = 0; i < 16; ++i) {
        const int dd = i * 4 + dr;
        const int s = s0 + sl;
        o[(size_t)(s >> 5) * (HD * 32) + dd * 32 + (s & 31)] = t[sl][dd];
    }
}

// Block = 4 waves, one 32-q tile. Wave w handles kv-tiles t = w, w+4, ... (split-K);
// swapped QK^T (mfma(K,Q)) -> lane owns q-row = lane&31; softmax in-register;
// LDS log-sum-exp combine of the 4 partials at the end.
__global__ __launch_bounds__(256, 3)
void attn32x4_kernel(const float* __restrict__ Q, const short* __restrict__ Kb,
                     const short* __restrict__ Vt, const unsigned* __restrict__ bitsT,
                     float* __restrict__ Out) {
    __shared__ float sml[2][4][32];      // [m|l][wave][qrow]
    __shared__ float oacc[4][32][68];    // [wave][qrow][d] (pad 68: <=4-way wr, aligned rd)

    const int bh   = blockIdx.y;
    const int tid  = threadIdx.x;
    const int wid  = tid >> 6;
    const int lane = tid & 63;
    const int la   = lane & 31;   // q-row / k-row / d-row for A-frags
    const int h    = lane >> 5;   // wave half
    const int qt   = gridDim.x - 1 - blockIdx.x;   // longest blocks first
    const int q0   = qt * 32;
    const int ntiles = qt + 1;
    const size_t base = (size_t)bh * SEQ * HD;

    // Q as MFMA B-operand: col=q=la, k-elem i of chunk j -> d = j*16 + h*8 + i
    bf16x8 qf[4];
    {
        const float* qp = Q + base + (size_t)(q0 + la) * HD + h * 8;
        #pragma unroll
        for (int j = 0; j < 4; ++j) {
            f32x4 a0 = *(const f32x4*)(qp + j * 16);
            f32x4 a1 = *(const f32x4*)(qp + j * 16 + 4);
            #pragma unroll
            for (int i = 0; i < 4; ++i) {
                qf[j][i]     = f2bf(a0[i] * QSC);
                qf[j][4 + i] = f2bf(a1[i] * QSC);
            }
        }
    }

    f32x16 acc_o0 = {0,0,0,0,0,0,0,0,0,0,0,0,0,0,0,0};
    f32x16 acc_o1 = {0,0,0,0,0,0,0,0,0,0,0,0,0,0,0,0};
    float m_run = -3e38f, l_run = 0.f;

    const short* Kbb = Kb + base;
    const short* Vtb = Vt + base;
    const unsigned* bq = bitsT + q0 + la;

    // preload first tile (branchless safe address for idle waves)
    const int t0 = (wid < ntiles) ? wid : 0;
    const short* kp0 = Kbb + (size_t)(t0 * 32 + la) * HD + h * 8;
    bf16x8 kfa = *(const bf16x8*)(kp0);
    bf16x8 kfb = *(const bf16x8*)(kp0 + 16);
    bf16x8 kfc = *(const bf16x8*)(kp0 + 32);
    bf16x8 kfd = *(const bf16x8*)(kp0 + 48);
    unsigned mw = bq[(size_t)t0 * SEQ];

    for (int t = wid; t < ntiles; t += 4) {
        // V^T A-frags for this tile
        const short* vt = Vtb + (size_t)t * (HD * 32) + la * 32 + h * 8;
        bf16x8 vf00 = *(const bf16x8*)(vt);
        bf16x8 vf01 = *(const bf16x8*)(vt + 16);
        bf16x8 vf10 = *(const bf16x8*)(vt + 32 * 32);
        bf16x8 vf11 = *(const bf16x8*)(vt + 32 * 32 + 16);

        // ---- QK^T swapped, two independent 2-MFMA chains ----
        f32x16 sA = {0,0,0,0,0,0,0,0,0,0,0,0,0,0,0,0};
        f32x16 sB = {0,0,0,0,0,0,0,0,0,0,0,0,0,0,0,0};
        __builtin_amdgcn_s_setprio(1);
        sA = __builtin_amdgcn_mfma_f32_32x32x16_bf16(kfa, qf[0], sA, 0, 0, 0);
        sB = __builtin_amdgcn_mfma_f32_32x32x16_bf16(kfc, qf[2], sB, 0, 0, 0);
        sA = __builtin_amdgcn_mfma_f32_32x32x16_bf16(kfb, qf[1], sA, 0, 0, 0);
        sB = __builtin_amdgcn_mfma_f32_32x32x16_bf16(kfd, qf[3], sB, 0, 0, 0);
        __builtin_amdgcn_s_setprio(0);

        // ---- prefetch next tile's K + mask (branchless clamp) ----
        const int tn = (t + 4 < ntiles) ? t + 4 : t;
        const short* kpn = Kbb + (size_t)(tn * 32 + la) * HD + h * 8;
        bf16x8 nka = *(const bf16x8*)(kpn);
        bf16x8 nkb = *(const bf16x8*)(kpn + 16);
        bf16x8 nkc = *(const bf16x8*)(kpn + 32);
        bf16x8 nkd = *(const bf16x8*)(kpn + 48);
        unsigned nmw = bq[(size_t)tn * SEQ];

        f32x16 s = sA + sB;

        // ---- row max (unmasked max is valid) + cross-half ----
        float mx = fmaxf(fmaxf(fmaxf(s[0], s[1]), fmaxf(s[2], s[3])),
                         fmaxf(fmaxf(s[4], s[5]), fmaxf(s[6], s[7])));
        mx = fmaxf(mx, fmaxf(fmaxf(fmaxf(s[8], s[9]), fmaxf(s[10], s[11])),
                             fmaxf(fmaxf(s[12], s[13]), fmaxf(s[14], s[15]))));
        mx = fmaxf(mx, __shfl_xor(mx, 32));
        const float mnew = fmaxf(m_run, mx);
        const float rsc = __builtin_amdgcn_exp2f(m_run - mnew);
        m_run = mnew;

        // ---- P = mask ? exp2(s - m) : 0   (k-row = (r&3) + 8*(r>>2) + 4h) ----
        const int bp = 4 * h;
        #pragma unroll
        for (int r = 0; r < 16; ++r) {
            float e = __builtin_amdgcn_exp2f(s[r] - mnew);
            s[r] = ((mw >> (bp + (r & 3) + 8 * (r >> 2))) & 1u) ? e : 0.f;
        }
        float ps = ((s[0] + s[1]) + (s[2] + s[3])) + ((s[4] + s[5]) + (s[6] + s[7]));
        ps += ((s[8] + s[9]) + (s[10] + s[11])) + ((s[12] + s[13]) + (s[14] + s[15]));
        ps += __shfl_xor(ps, 32);
        l_run = l_run * rsc + ps;
        #pragma unroll
        for (int r = 0; r < 16; ++r) { acc_o0[r] *= rsc; acc_o1[r] *= rsc; }

        // ---- pack P^T into B-frags (elem i of half h <-> k = 8h+i), validated r4 ----
        {
            unsigned a0 = cvt2(s[0], s[1]),  a1 = cvt2(s[2], s[3]);
            unsigned b0 = cvt2(s[4], s[5]),  b1 = cvt2(s[6], s[7]);
            unsigned d0 = h ? a0 : b0;
            unsigned d1 = h ? a1 : b1;
            unsigned e0 = __shfl_xor(d0, 32);
            unsigned e1 = __shfl_xor(d1, 32);
            u32x4 t1 = h ? u32x4{e0, e1, b0, b1}
                         : u32x4{a0, a1, e0, e1};
            bf16x8 pb1 = __builtin_bit_cast(bf16x8, t1);

            unsigned a2 = cvt2(s[8], s[9]),   a3 = cvt2(s[10], s[11]);
            unsigned b2 = cvt2(s[12], s[13]), b3 = cvt2(s[14], s[15]);
            unsigned d2 = h ? a2 : b2;
            unsigned d3 = h ? a3 : b3;
            unsigned e2 = __shfl_xor(d2, 32);
            unsigned e3 = __shfl_xor(d3, 32);
            u32x4 t2 = h ? u32x4{e2, e3, b2, b3}
                         : u32x4{a2, a3, e2, e3};
            bf16x8 pb2 = __builtin_bit_cast(bf16x8, t2);

            // ---- PV: O^T[d][q] += V^T[d][k] * P^T[k][q] ----
            __builtin_amdgcn_s_setprio(1);
            acc_o0 = __builtin_amdgcn_mfma_f32_32x32x16_bf16(vf00, pb1, acc_o0, 0, 0, 0);
            acc_o1 = __builtin_amdgcn_mfma_f32_32x32x16_bf16(vf10, pb1, acc_o1, 0, 0, 0);
            acc_o0 = __builtin_amdgcn_mfma_f32_32x32x16_bf16(vf01, pb2, acc_o0, 0, 0, 0);
            acc_o1 = __builtin_amdgcn_mfma_f32_32x32x16_bf16(vf11, pb2, acc_o1, 0, 0, 0);
            __builtin_amdgcn_s_setprio(0);
        }

        kfa = nka; kfb = nkb; kfc = nkc; kfd = nkd; mw = nmw;
    }

    // ---- combine the 4 split-K partials (log-sum-exp merge in exp2 domain) ----
    if (h == 0) { sml[0][wid][la] = m_run; sml[1][wid][la] = l_run; }
    __syncthreads();

    {
        const float M = fmaxf(fmaxf(sml[0][0][la], sml[0][1][la]),
                              fmaxf(sml[0][2][la], sml[0][3][la]));
        const float f = __builtin_amdgcn_exp2f(m_run - M);   // 0 for idle waves
        #pragma unroll
        for (int r = 0; r < 16; ++r) {
            const int d0 = (r & 3) + 8 * (r >> 2) + 4 * h;
            oacc[wid][la][d0]      = acc_o0[r] * f;
            oacc[wid][la][32 + d0] = acc_o1[r] * f;
        }
    }
    __syncthreads();

    {
        const int q  = tid >> 3;         // 0..31
        const int dc = (tid & 7) * 8;    // 0..56
        const float Mq = fmaxf(fmaxf(sml[0][0][q], sml[0][1][q]),
                               fmaxf(sml[0][2][q], sml[0][3][q]));
        float Lq = 0.f;
        #pragma unroll
        for (int w = 0; w < 4; ++w)
            Lq += __builtin_amdgcn_exp2f(sml[0][w][q] - Mq) * sml[1][w][q];
        const float inv = 1.f / Lq;
        f32x4 o0 = {0,0,0,0}, o1 = {0,0,0,0};
        #pragma unroll
        for (int w = 0; w < 4; ++w) {
            o0 += *(const f32x4*)&oacc[w][q][dc];
            o1 += *(const f32x4*)&oacc[w][q][dc + 4];
        }
        float* op = Out + base + (size_t)(q0 + q) * HD + dc;
        *(f32x4*)op       = o0 * inv;
        *(f32x4*)(op + 4) = o1 * inv;
    }
}

// ---------------- fallback (round-1 kernel) if ws too small ----------------
__global__ __launch_bounds__(256)
void attn_kernel(const float* __restrict__ Q, const float* __restrict__ K,
                 const float* __restrict__ V, const unsigned char* __restrict__ mask,
                 const int* __restrict__ flag, float* __restrict__ Out) {
    __shared__ short plds[4][16][40];
    const int esz  = *flag;
    const int bh   = blockIdx.y;
    const int wid  = threadIdx.x >> 6;
    const int lane = threadIdx.x & 63;
    const int l16  = lane & 15;
    const int hi   = lane >> 4;
    const int q0   = blockIdx.x * 64 + wid * 16;
    const size_t base = (size_t)bh * SEQ * HD;
    const float* Qb = Q + base;
    const float* Kb = K + base;
    const float* Vb = V + base;
    const unsigned int* mask32 = (const unsigned int*)mask;
    bf16x8 qf[2];
    {
        const float* qp = Qb + (size_t)(q0 + l16) * HD + hi * 8;
        f32x4 a0 = *(const f32x4*)(qp);
        f32x4 a1 = *(const f32x4*)(qp + 4);
        f32x4 a2 = *(const f32x4*)(qp + 32);
        f32x4 a3 = *(const f32x4*)(qp + 36);
        #pragma unroll
        for (int i = 0; i < 4; ++i) {
            qf[0][i] = f2bf(a0[i]); qf[0][4 + i] = f2bf(a1[i]);
            qf[1][i] = f2bf(a2[i]); qf[1][4 + i] = f2bf(a3[i]);
        }
    }
    f32x4 acc_o[4] = {f32x4{0,0,0,0}, f32x4{0,0,0,0}, f32x4{0,0,0,0}, f32x4{0,0,0,0}};
    float m_run[4], l_run[4];
    #pragma unroll
    for (int j = 0; j < 4; ++j) { m_run[j] = -__builtin_inff(); l_run[j] = 0.f; }
    const int kv_end = q0 + 16;
    for (int kv = 0; kv < kv_end; kv += 32) {
        f32x4 acc_s[2] = {f32x4{0,0,0,0}, f32x4{0,0,0,0}};
        #pragma unroll
        for (int t = 0; t < 2; ++t) {
            const float* kp = Kb + (size_t)(kv + 16 * t + l16) * HD + hi * 8;
            f32x4 b0 = *(const f32x4*)(kp);
            f32x4 b1 = *(const f32x4*)(kp + 4);
            f32x4 b2 = *(const f32x4*)(kp + 32);
            f32x4 b3 = *(const f32x4*)(kp + 36);
            bf16x8 kf0, kf1;
            #pragma unroll
            for (int i = 0; i < 4; ++i) {
                kf0[i] = f2bf(b0[i]); kf0[4 + i] = f2bf(b1[i]);
                kf1[i] = f2bf(b2[i]); kf1[4 + i] = f2bf(b3[i]);
            }
            acc_s[t] = __builtin_amdgcn_mfma_f32_16x16x32_bf16(qf[0], kf0, acc_s[t], 0, 0, 0);
            acc_s[t] = __builtin_amdgcn_mfma_f32_16x16x32_bf16(qf[1], kf1, acc_s[t], 0, 0, 0);
        }
        float s[2][4];
        #pragma unroll
        for (int t = 0; t < 2; ++t) {
            const int k = kv + 16 * t + l16;
            #pragma unroll
            for (int j = 0; j < 4; ++j) {
                const int qrow = q0 + hi * 4 + j;
                const size_t midx = (size_t)qrow * SEQ + k;
                const bool mv = (esz == 1) ? (mask[midx] != 0) : (mask32[midx] != 0);
                s[t][j] = mv ? acc_s[t][j] * SCALE : -__builtin_inff();
            }
        }
        float mnew[4], r[4];
        #pragma unroll
        for (int j = 0; j < 4; ++j) {
            float v = fmaxf(s[0][j], s[1][j]);
            #pragma unroll
            for (int off = 1; off < 16; off <<= 1) v = fmaxf(v, __shfl_xor(v, off));
            mnew[j] = fmaxf(m_run[j], v);
            r[j] = (m_run[j] > -__builtin_inff()) ? __expf(m_run[j] - mnew[j]) : 0.f;
        }
        float p[2][4];
        #pragma unroll
        for (int j = 0; j < 4; ++j) {
            float ps = 0.f;
            #pragma unroll
            for (int t = 0; t < 2; ++t) {
                p[t][j] = (s[t][j] > -__builtin_inff()) ? __expf(s[t][j] - mnew[j]) : 0.f;
                ps += p[t][j];
            }
            #pragma unroll
            for (int off = 1; off < 16; off <<= 1) ps += __shfl_xor(ps, off);
            l_run[j] = l_run[j] * r[j] + ps;
            m_run[j] = mnew[j];
            #pragma unroll
            for (int t2 = 0; t2 < 4; ++t2) acc_o[t2][j] *= r[j];
        }
        #pragma unroll
        for (int t = 0; t < 2; ++t)
            #pragma unroll
            for (int j = 0; j < 4; ++j)
                plds[wid][hi * 4 + j][16 * t + l16] = f2bf(p[t][j]);
        bf16x8 pa = *(bf16x8*)&plds[wid][l16][hi * 8];
        #pragma unroll
        for (int t2 = 0; t2 < 4; ++t2) {
            const float* vp = Vb + (size_t)(kv + hi * 8) * HD + 16 * t2 + l16;
            bf16x8 vf;
            #pragma unroll
            for (int i = 0; i < 8; ++i) vf[i] = f2bf(vp[(size_t)i * HD]);
            acc_o[t2] = __builtin_amdgcn_mfma_f32_16x16x32_bf16(pa, vf, acc_o[t2], 0, 0, 0);
        }
    }
    #pragma unroll
    for (int j = 0; j < 4; ++j) {
        const float inv = 1.f / l_run[j];
        const int qrow = q0 + hi * 4 + j;
        float* op = Out + base + (size_t)qrow * HD + l16;
        #pragma unroll
        for (int t2 = 0; t2 < 4; ++t2) op[16 * t2] = acc_o[t2][j] * inv;
    }
}

extern "C" void kernel_launch(void* const* d_in, const int* in_sizes, int n_in,
                              void* d_out, int out_size, void* d_ws, size_t ws_size,
                              hipStream_t stream) {
    const float* Q = (const float*)d_in[0];
    const float* K = (const float*)d_in[1];
    const float* V = (const float*)d_in[2];
    const unsigned char* mask = (const unsigned char*)d_in[3];

    const size_t bitsB = (size_t)SEQ * (SEQ / 32) * 4;          // 512 KB
    const size_t kvB   = (size_t)NBH * SEQ * HD * 2;            // 8 MB
    const size_t need  = bitsB + 2 * kvB + 256;

    if (ws_size >= need) {
        unsigned* bits = (unsigned*)d_ws;
        short* Kb = (short*)((char*)d_ws + bitsB);
        short* Vt = (short*)((char*)d_ws + bitsB + kvB);
        int* flag = (int*)((char*)d_ws + bitsB + 2 * kvB);

        detect_mask_kernel<<<dim3(1), dim3(64), 0, stream>>>(mask, in_sizes[3], flag);
        bitpack_mask_kernel<<<dim3(SEQ * (SEQ / 32) / 256), dim3(256), 0, stream>>>(mask, flag, bits);
        convert_k_kernel<<<dim3((NBH * SEQ * HD / 8) / 256), dim3(256), 0, stream>>>(K, Kb);
        transpose_v_kernel<<<dim3(SEQ / 64, NBH), dim3(256), 0, stream>>>(V, Vt);
        attn32x4_kernel<<<dim3(SEQ / 32, NBH), dim3(256), 0, stream>>>(Q, Kb, Vt, bits, (float*)d_out);
    } else {
        int* flag = (int*)d_ws;
        detect_mask_kernel<<<dim3(1), dim3(64), 0, stream>>>(mask, in_sizes[3], flag);
        attn_kernel<<<dim3(SEQ / 64, NBH), dim3(256), 0, stream>>>(Q, K, V, mask, flag, (float*)d_out);
    }
}